// Round 1
// baseline (314.453 us; speedup 1.0000x reference)
//
#include <hip/hip_runtime.h>
#include <hip/hip_bf16.h>

#define BSZ 131072

typedef __bf16 v8bf __attribute__((ext_vector_type(8)));
typedef float f32x4 __attribute__((ext_vector_type(4)));

constexpr int RPB = 128;       // rows per block
constexpr int NTHREADS = 512;  // 8 waves
constexpr int LDA  = 264;      // 256 + 8 pad (16B aligned rows, breaks bank conflicts)
constexpr int LDA3 = 72;       // 64 + 8 pad

// d_ws layout (bf16 element offsets) — fragment-swizzled B operands
constexpr int OFF_B2T = 0;        // z2 : B[k][n] = Vw2[n][k]   (256x256)
constexpr int OFF_U2T = 65536;    // U2 : B[k][n] = Uw2[n][k]   (256x256)
constexpr int OFF_B2  = 131072;   // s2 : B[k][n] = Vw2[k][n]   (256x256)
constexpr int OFF_B3T = 196608;   // z3 : B[k][n] = Vw3[n][k]   (256x64)
constexpr int OFF_B3  = 212992;   // t3 : B[k][n] = Vw3[k][n]   (64x256)
constexpr int WS_ELEMS = 229376;

__device__ __forceinline__ float tanhf_fast(float x){
  float e = __expf(2.0f * x);
  return 1.0f - 2.0f / (e + 1.0f);   // exact at +-inf, no NaN
}

__device__ __forceinline__ __bf16 f2bf(float f){
  return __builtin_bit_cast(__bf16, __float2bfloat16(f)); // RNE
}

// ---- weight pre-swizzle: one thread per bf16 element of ws ----
// Fragment storage: frag f=(kstep*NT+ntile); lane l holds 8 contiguous bf16:
//   element j of lane l = B[kstep*32 + (l>>4)*8 + j][ntile*16 + (l&15)]
__global__ void prep_weights(const float* __restrict__ Vw2,
                             const float* __restrict__ Uw2,
                             const float* __restrict__ Vw3,
                             __bf16* __restrict__ ws){
  int e = blockIdx.x * 256 + threadIdx.x;
  int idx, NT, base; const float* W; bool trans;
  if      (e <  65536){ idx = e;          W = Vw2; trans = true;  NT = 16; base = OFF_B2T; }
  else if (e < 131072){ idx = e - 65536;  W = Uw2; trans = true;  NT = 16; base = OFF_U2T; }
  else if (e < 196608){ idx = e - 131072; W = Vw2; trans = false; NT = 16; base = OFF_B2;  }
  else if (e < 212992){ idx = e - 196608; W = Vw3; trans = true;  NT = 4;  base = OFF_B3T; }
  else                { idx = e - 212992; W = Vw3; trans = false; NT = 16; base = OFF_B3;  }
  int j = idx & 7, l = (idx >> 3) & 63, f = idx >> 9;
  int nt = f % NT, ks = f / NT;
  int k = ks * 32 + (l >> 4) * 8 + j;
  int n = nt * 16 + (l & 15);
  float v = trans ? W[n * 256 + k] : W[k * 256 + n];
  ws[base + idx] = f2bf(v);
}

__global__ __launch_bounds__(NTHREADS, 2) void fused_clf(
    const float* __restrict__ x,
    const float* __restrict__ Vw1, const float* __restrict__ Vb1,
    const float* __restrict__ Vb2, const float* __restrict__ Vb3,
    const float* __restrict__ Uw1, const float* __restrict__ Ub1,
    const float* __restrict__ Ub2,
    const float* __restrict__ Uw3, const float* __restrict__ Ub3,
    const __bf16* __restrict__ ws,
    float* __restrict__ out)
{
  __shared__ float  xs[RPB][4];
  __shared__ __bf16 b1[RPB][LDA];    // u2 | a1 -> s2'
  __shared__ __bf16 b2[RPB][LDA];    // u1 | a2 -> t2'
  __shared__ __bf16 b3[RPB][LDA3];   // a3
  __shared__ float  utile[RPB];
  __shared__ float  red[RPB][4];

  const int tid  = threadIdx.x;
  const int lane = tid & 63;
  const int wave = tid >> 6;
  const int wm   = wave >> 1;      // 0..3 : which 32-row slab
  const int wn   = wave & 1;       // 0..1 : which 128-col half
  const int quad = lane >> 4;
  const int l16  = lane & 15;
  const int row0 = blockIdx.x * RPB;
  const int r0   = wm * 32;

  { int b = tid >> 2, k = tid & 3;
    xs[b][k] = x[(row0 + b) * 4 + k]; }
  __syncthreads();

  // layer-1 (K=4) in fp32, write tanh result as bf16
  auto layer1 = [&](const float* __restrict__ W1, const float* __restrict__ bv,
                    __bf16 (*dst)[LDA]){
    const float4* W14 = (const float4*)W1;
    #pragma unroll 4
    for (int e = tid; e < RPB * 256; e += NTHREADS){
      int i = e & 255, b = e >> 8;
      float4 w = W14[i];
      float z = bv[i] + xs[b][0]*w.x + xs[b][1]*w.y + xs[b][2]*w.z + xs[b][3]*w.w;
      dst[b][i] = f2bf(tanhf_fast(z));
    }
  };

  // (128x256)x(256x256) MFMA GEMM. epi==0: dst = tanh(acc+bias).
  // epi==1: dst = acc * (1 - dst^2)  (in-place, owner-lane slots)
  auto gemm256 = [&](const __bf16 (*A)[LDA], const __bf16* __restrict__ Bw,
                     const float* __restrict__ bias, __bf16 (*dst)[LDA], int epi){
    f32x4 acc[2][8];
    #pragma unroll
    for (int m = 0; m < 2; m++)
      #pragma unroll
      for (int n = 0; n < 8; n++){ f32x4 z = {0.f,0.f,0.f,0.f}; acc[m][n] = z; }
    const v8bf* B = (const v8bf*)Bw;
    #pragma unroll
    for (int kk = 0; kk < 8; kk++){
      v8bf a0 = *(const v8bf*)&A[r0 + l16     ][kk*32 + quad*8];
      v8bf a1 = *(const v8bf*)&A[r0 + 16 + l16][kk*32 + quad*8];
      #pragma unroll
      for (int nt = 0; nt < 8; nt++){
        v8bf bf = B[(kk*16 + wn*8 + nt)*64 + lane];
        acc[0][nt] = __builtin_amdgcn_mfma_f32_16x16x32_bf16(a0, bf, acc[0][nt], 0,0,0);
        acc[1][nt] = __builtin_amdgcn_mfma_f32_16x16x32_bf16(a1, bf, acc[1][nt], 0,0,0);
      }
    }
    #pragma unroll
    for (int m = 0; m < 2; m++){
      int rb = r0 + m*16 + quad*4;
      #pragma unroll
      for (int nt = 0; nt < 8; nt++){
        int col = (wn*8 + nt)*16 + l16;
        float bvv = (epi == 0) ? bias[col] : 0.0f;
        #pragma unroll
        for (int r = 0; r < 4; r++){
          float v = acc[m][nt][r] + bvv;
          if (epi == 0){
            dst[rb + r][col] = f2bf(tanhf_fast(v));
          } else {
            float a = (float)dst[rb + r][col];
            dst[rb + r][col] = f2bf(v * (1.0f - a*a));
          }
        }
      }
    }
  };

  // ================= U network =================
  layer1(Uw1, Ub1, b2);                    // u1 -> b2
  __syncthreads();
  gemm256(b2, ws + OFF_U2T, Ub2, b1, 0);   // u2 -> b1
  __syncthreads();
  { int b = tid >> 2, seg = tid & 3;       // u2 . Uw3
    float p = 0.f;
    #pragma unroll 8
    for (int m = seg*64; m < seg*64 + 64; m++)
      p += (float)b1[b][m] * Uw3[m];
    red[b][seg] = p; }
  __syncthreads();
  if (tid < RPB){
    float z = red[tid][0] + red[tid][1] + red[tid][2] + red[tid][3] + Ub3[0];
    float u = tanhf_fast(z) * 20.0f;
    utile[tid] = u;
    out[row0 + tid] = u;
  }
  __syncthreads();

  // ================= V network forward =================
  layer1(Vw1, Vb1, b1);                    // a1 -> b1
  __syncthreads();
  gemm256(b1, ws + OFF_B2T, Vb2, b2, 0);   // a2 -> b2
  __syncthreads();

  // z3: a2 @ Vw3^T -> a3 (128x64) in b3
  {
    f32x4 acc[2][2];
    #pragma unroll
    for (int m = 0; m < 2; m++){ f32x4 z = {0.f,0.f,0.f,0.f}; acc[m][0] = z; acc[m][1] = z; }
    const v8bf* B = (const v8bf*)(ws + OFF_B3T);
    #pragma unroll
    for (int kk = 0; kk < 8; kk++){
      v8bf a0 = *(const v8bf*)&b2[r0 + l16     ][kk*32 + quad*8];
      v8bf a1 = *(const v8bf*)&b2[r0 + 16 + l16][kk*32 + quad*8];
      #pragma unroll
      for (int nt = 0; nt < 2; nt++){
        v8bf bf = B[(kk*4 + wn*2 + nt)*64 + lane];
        acc[0][nt] = __builtin_amdgcn_mfma_f32_16x16x32_bf16(a0, bf, acc[0][nt], 0,0,0);
        acc[1][nt] = __builtin_amdgcn_mfma_f32_16x16x32_bf16(a1, bf, acc[1][nt], 0,0,0);
      }
    }
    #pragma unroll
    for (int m = 0; m < 2; m++){
      int rb = r0 + m*16 + quad*4;
      #pragma unroll
      for (int nt = 0; nt < 2; nt++){
        int col = (wn*2 + nt)*16 + l16;
        float bvv = Vb3[col];
        #pragma unroll
        for (int r = 0; r < 4; r++)
          b3[rb + r][col] = f2bf(tanhf_fast(acc[m][nt][r] + bvv));
      }
    }
  }
  __syncthreads();

  // V = 0.5 * sum(a3^2)
  { int b = tid >> 2, seg = tid & 3;
    float p = 0.f;
    #pragma unroll
    for (int i = seg*16; i < seg*16 + 16; i++){
      float a = (float)b3[b][i]; p += a*a; }
    red[b][seg] = p; }
  __syncthreads();
  if (tid < RPB)
    out[BSZ + row0 + tid] = 0.5f * (red[tid][0] + red[tid][1] + red[tid][2] + red[tid][3]);

  // t3 = (a3*(1-a3^2)) @ Vw3 ; then t2' = t3*(1-a2^2) in-place into b2
  {
    f32x4 acc[2][8];
    #pragma unroll
    for (int m = 0; m < 2; m++)
      #pragma unroll
      for (int n = 0; n < 8; n++){ f32x4 z = {0.f,0.f,0.f,0.f}; acc[m][n] = z; }
    const v8bf* B = (const v8bf*)(ws + OFF_B3);
    #pragma unroll
    for (int kk = 0; kk < 2; kk++){
      v8bf a0r = *(const v8bf*)&b3[r0 + l16     ][kk*32 + quad*8];
      v8bf a1r = *(const v8bf*)&b3[r0 + 16 + l16][kk*32 + quad*8];
      v8bf a0, a1;
      #pragma unroll
      for (int j = 0; j < 8; j++){
        float av = (float)a0r[j]; a0[j] = f2bf(av * (1.0f - av*av));
        float bw = (float)a1r[j]; a1[j] = f2bf(bw * (1.0f - bw*bw));
      }
      #pragma unroll
      for (int nt = 0; nt < 8; nt++){
        v8bf bf = B[(kk*16 + wn*8 + nt)*64 + lane];
        acc[0][nt] = __builtin_amdgcn_mfma_f32_16x16x32_bf16(a0, bf, acc[0][nt], 0,0,0);
        acc[1][nt] = __builtin_amdgcn_mfma_f32_16x16x32_bf16(a1, bf, acc[1][nt], 0,0,0);
      }
    }
    #pragma unroll
    for (int m = 0; m < 2; m++){
      int rb = r0 + m*16 + quad*4;
      #pragma unroll
      for (int nt = 0; nt < 8; nt++){
        int col = (wn*8 + nt)*16 + l16;
        #pragma unroll
        for (int r = 0; r < 4; r++){
          float a = (float)b2[rb + r][col];
          b2[rb + r][col] = f2bf(acc[m][nt][r] * (1.0f - a*a));
        }
      }
    }
  }
  __syncthreads();

  gemm256(b2, ws + OFF_B2, nullptr, b1, 1);  // s2' = (t2'@Vw2)*(1-a1^2) -> b1
  __syncthreads();

  // grad_V[b][k] = sum_m s2'[b][m] * Vw1[m][k]
  { int b = tid >> 2, k = tid & 3;
    float sgv = 0.f;
    #pragma unroll 8
    for (int m = 0; m < 256; m++)
      sgv += (float)b1[b][m] * Vw1[m*4 + k];
    red[b][k] = sgv; }
  __syncthreads();

  // dynamics + Vdot
  if (tid < RPB){
    int b = tid;
    float th = xs[b][1], vv = xs[b][2], om = xs[b][3];
    float c = cosf(th), s = sinf(th);
    float dc  = c - 24.7f;
    float dc2 = c*c - 24.7f;
    float f2v = (c*(9.8f*s + 11.5f*vv) + 68.4f*vv - 1.2f*om*om*s) / dc;
    float f3v = (-58.8f*vv*c - 243.5f*vv - s*(208.3f + om*om*c)) / dc2;
    float g2v = (-1.8f*c - 10.9f) / dc;
    float g3v = (9.3f*c + 38.6f) / dc2;
    float Lf = red[b][0]*vv + red[b][1]*om + red[b][2]*f2v + red[b][3]*f3v;
    float Lg = red[b][2]*g2v + red[b][3]*g3v;
    out[2*BSZ + row0 + b] = Lf + Lg * utile[b];
  }
}

extern "C" void kernel_launch(void* const* d_in, const int* in_sizes, int n_in,
                              void* d_out, int out_size, void* d_ws, size_t ws_size,
                              hipStream_t stream) {
  const float* x   = (const float*)d_in[0];
  const float* Vw1 = (const float*)d_in[1];
  const float* Vb1 = (const float*)d_in[2];
  const float* Vw2 = (const float*)d_in[3];
  const float* Vb2 = (const float*)d_in[4];
  const float* Vw3 = (const float*)d_in[5];
  const float* Vb3 = (const float*)d_in[6];
  const float* Uw1 = (const float*)d_in[7];
  const float* Ub1 = (const float*)d_in[8];
  const float* Uw2 = (const float*)d_in[9];
  const float* Ub2 = (const float*)d_in[10];
  const float* Uw3 = (const float*)d_in[11];
  const float* Ub3 = (const float*)d_in[12];
  __bf16* ws = (__bf16*)d_ws;
  float* out = (float*)d_out;

  hipLaunchKernelGGL(prep_weights, dim3(WS_ELEMS / 256), dim3(256), 0, stream,
                     Vw2, Uw2, Vw3, ws);
  hipLaunchKernelGGL(fused_clf, dim3(BSZ / RPB), dim3(NTHREADS), 0, stream,
                     x, Vw1, Vb1, Vb2, Vb3, Uw1, Ub1, Ub2, Uw3, Ub3, ws, out);
}

// Round 2
// 206.808 us; speedup vs baseline: 1.5205x; 1.5205x over previous
//
#include <hip/hip_runtime.h>
#include <hip/hip_bf16.h>

#define BSZ 131072

typedef __bf16 v8bf __attribute__((ext_vector_type(8)));
typedef float f32x4 __attribute__((ext_vector_type(4)));

constexpr int RPB = 64;        // rows per block
constexpr int NTHREADS = 512;  // 8 waves
constexpr int LDA = 264;       // 256 + 8 pad: row stride 132 dwords == 4 mod 32 banks

// d_ws layout (bf16 element offsets) — fragment-swizzled B operands
constexpr int OFF_B2T = 0;        // z2 : B[k][n] = Vw2[n][k]   (256x256) NT=16
constexpr int OFF_U2T = 65536;    // U2 : B[k][n] = Uw2[n][k]   (256x256) NT=16
constexpr int OFF_B2  = 131072;   // s2 : B[k][n] = Vw2[k][n]   (256x256) NT=16
constexpr int OFF_B3T = 196608;   // z3 : B[k][n] = Vw3[n][k]   (256x64)  NT=4
constexpr int OFF_B3  = 212992;   // t3 : B[k][n] = Vw3[k][n]   (64x256)  NT=16
constexpr int OFF_U3  = 229376;   // u3 : B[k][0] = Uw3[k], cols 1..15 zero (256x16) NT=1
constexpr int OFF_GV  = 233472;   // gV : B[k][n] = Vw1[k][n] n<4 else 0  (256x16) NT=1
constexpr int WS_ELEMS = 237568;

__device__ __forceinline__ float tanhf_fast(float x){
  float e = __expf(2.0f * x);
  return 1.0f - 2.0f / (e + 1.0f);   // exact at +-inf, no NaN
}

__device__ __forceinline__ __bf16 f2bf(float f){
  return __builtin_bit_cast(__bf16, __float2bfloat16(f)); // RNE
}

// ---- weight pre-swizzle: one thread per bf16 element of ws ----
// Fragment storage: frag f=(kstep*NT+ntile); lane l holds 8 contiguous bf16:
//   element j of lane l = B[kstep*32 + (l>>4)*8 + j][ntile*16 + (l&15)]
__global__ void prep_weights(const float* __restrict__ Vw2,
                             const float* __restrict__ Uw2,
                             const float* __restrict__ Vw3,
                             const float* __restrict__ Vw1,
                             const float* __restrict__ Uw3,
                             __bf16* __restrict__ ws){
  int e = blockIdx.x * 256 + threadIdx.x;
  if (e >= WS_ELEMS) return;
  int idx, NT, base, mode; const float* W;
  if      (e <  65536){ idx = e;          W = Vw2; mode = 0; NT = 16; base = OFF_B2T; }
  else if (e < 131072){ idx = e - 65536;  W = Uw2; mode = 0; NT = 16; base = OFF_U2T; }
  else if (e < 196608){ idx = e - 131072; W = Vw2; mode = 1; NT = 16; base = OFF_B2;  }
  else if (e < 212992){ idx = e - 196608; W = Vw3; mode = 0; NT = 4;  base = OFF_B3T; }
  else if (e < 229376){ idx = e - 212992; W = Vw3; mode = 1; NT = 16; base = OFF_B3;  }
  else if (e < 233472){ idx = e - 229376; W = Uw3; mode = 2; NT = 1;  base = OFF_U3;  }
  else                { idx = e - 233472; W = Vw1; mode = 3; NT = 1;  base = OFF_GV;  }
  int j = idx & 7, l = (idx >> 3) & 63, f = idx >> 9;
  int nt = f % NT, ks = f / NT;
  int k = ks * 32 + (l >> 4) * 8 + j;
  int n = nt * 16 + (l & 15);
  float v;
  if      (mode == 0) v = W[n * 256 + k];
  else if (mode == 1) v = W[k * 256 + n];
  else if (mode == 2) v = (n == 0) ? W[k] : 0.0f;
  else                v = (n < 4)  ? W[k * 4 + n] : 0.0f;
  ws[base + idx] = f2bf(v);
}

__global__ __launch_bounds__(NTHREADS, 4) void fused_clf(
    const float* __restrict__ x,
    const float* __restrict__ Vw1, const float* __restrict__ Vb1,
    const float* __restrict__ Vb2, const float* __restrict__ Vb3,
    const float* __restrict__ Uw1, const float* __restrict__ Ub1,
    const float* __restrict__ Ub2, const float* __restrict__ Ub3,
    const __bf16* __restrict__ ws,
    float* __restrict__ out)
{
  __shared__ __bf16 b1[RPB][LDA];     // u2 | a1 -> s2'
  __shared__ __bf16 b2[RPB][LDA];     // u1 | a2 -> t2'
  __shared__ union alignas(16) S3 {   // aliased: b3 live z3..t3; r4 live U3-reduce & gradV
    __bf16 b3[RPB][72];               // a3' = a3*(1-a3^2)
    float  r4[8][RPB][4];             // per-wave MFMA reduction partials
  } s3;
  __shared__ float4 xs4[RPB];
  __shared__ float  red[RPB][4];
  __shared__ float  utile[RPB];

  const int tid  = threadIdx.x;
  const int lane = tid & 63;
  const int wave = tid >> 6;       // 0..7, owns n-tiles {2w, 2w+1} (cols w*32..w*32+31)
  const int quad = lane >> 4;
  const int l16  = lane & 15;
  const int row0 = blockIdx.x * RPB;

  if (tid < RPB) xs4[tid] = ((const float4*)x)[row0 + tid];
  __syncthreads();

  // ---- layer-1 (K=4) in fp32: each thread owns one column, 32 rows ----
  auto layer1 = [&](const float* __restrict__ W1, const float* __restrict__ bv,
                    __bf16 (*dst)[LDA]){
    int i  = tid & 255;
    int b0 = tid >> 8;
    float4 w  = ((const float4*)W1)[i];
    float  bb = bv[i];
    #pragma unroll
    for (int k = 0; k < 32; k++){
      int b = b0 + 2 * k;
      float4 xv = xs4[b];
      float z = bb + xv.x*w.x + xv.y*w.y + xv.z*w.z + xv.w*w.w;
      dst[b][i] = f2bf(tanhf_fast(z));
    }
  };

  // ---- (64x256)x(256x256): wave = 2 n-tiles, all 4 m-tiles. B read once/block. ----
  // epi==0: dst = tanh(acc+bias). epi==1: dst = acc*(1-dst^2) in place.
  auto gemm256 = [&](const __bf16 (*A)[LDA], const __bf16* __restrict__ Bw,
                     const float* __restrict__ bias, __bf16 (*dst)[LDA], int epi){
    f32x4 acc[4][2];
    #pragma unroll
    for (int m = 0; m < 4; m++){ f32x4 z={0.f,0.f,0.f,0.f}; acc[m][0]=z; acc[m][1]=z; }
    const v8bf* B = (const v8bf*)Bw;
    #pragma unroll
    for (int kk = 0; kk < 8; kk++){
      v8bf a[4];
      #pragma unroll
      for (int m = 0; m < 4; m++)
        a[m] = *(const v8bf*)&A[m*16 + l16][kk*32 + quad*8];
      #pragma unroll
      for (int nt = 0; nt < 2; nt++){
        v8bf bf = B[(kk*16 + wave*2 + nt)*64 + lane];
        #pragma unroll
        for (int m = 0; m < 4; m++)
          acc[m][nt] = __builtin_amdgcn_mfma_f32_16x16x32_bf16(a[m], bf, acc[m][nt], 0,0,0);
      }
    }
    #pragma unroll
    for (int m = 0; m < 4; m++){
      int rb = m*16 + quad*4;
      #pragma unroll
      for (int nt = 0; nt < 2; nt++){
        int col = (wave*2 + nt)*16 + l16;
        float bvv = (epi == 0) ? bias[col] : 0.0f;
        #pragma unroll
        for (int r = 0; r < 4; r++){
          float v = acc[m][nt][r] + bvv;
          if (epi == 0){
            dst[rb + r][col] = f2bf(tanhf_fast(v));
          } else {
            float a1v = (float)dst[rb + r][col];
            dst[rb + r][col] = f2bf(v * (1.0f - a1v*a1v));
          }
        }
      }
    }
  };

  // ---- N=16 MFMA reduction partial: C partial over kk=wave, store valid cols ----
  auto mfma_reduce = [&](const __bf16 (*A)[LDA], const __bf16* __restrict__ Bw,
                         int ncols){
    f32x4 acc[4];
    #pragma unroll
    for (int m = 0; m < 4; m++){ f32x4 z={0.f,0.f,0.f,0.f}; acc[m]=z; }
    const v8bf* B = (const v8bf*)Bw;
    v8bf bf = B[wave*64 + lane];           // frag kk = wave (NT=1)
    #pragma unroll
    for (int m = 0; m < 4; m++){
      v8bf a = *(const v8bf*)&A[m*16 + l16][wave*32 + quad*8];
      acc[m] = __builtin_amdgcn_mfma_f32_16x16x32_bf16(a, bf, acc[m], 0,0,0);
    }
    if (l16 < ncols){
      #pragma unroll
      for (int m = 0; m < 4; m++)
        #pragma unroll
        for (int r = 0; r < 4; r++)
          s3.r4[wave][m*16 + quad*4 + r][l16] = acc[m][r];
    }
  };

  // ================= U network =================
  layer1(Uw1, Ub1, b2);                    // u1 -> b2
  __syncthreads();
  gemm256(b2, ws + OFF_U2T, Ub2, b1, 0);   // u2 -> b1
  __syncthreads();
  mfma_reduce(b1, ws + OFF_U3, 1);         // u2 . Uw3 partials -> r4
  __syncthreads();
  if (tid < RPB){
    float z = Ub3[0];
    #pragma unroll
    for (int w = 0; w < 8; w++) z += s3.r4[w][tid][0];
    float u = tanhf_fast(z) * 20.0f;
    utile[tid] = u;
    out[row0 + tid] = u;
  }
  // ================= V network forward =================
  layer1(Vw1, Vb1, b1);                    // a1 -> b1 (u2 consumed; r4/b1 disjoint)
  __syncthreads();
  gemm256(b1, ws + OFF_B2T, Vb2, b2, 0);   // a2 -> b2
  __syncthreads();

  // z3: a2 @ Vw3^T. waves 0..3 (one 16-col tile each). Fused: V row-partials via
  // shfl butterfly; store a3' = a3*(1-a3^2) to b3 for the backward.
  if (wave < 4){
    f32x4 acc[4];
    #pragma unroll
    for (int m = 0; m < 4; m++){ f32x4 z={0.f,0.f,0.f,0.f}; acc[m]=z; }
    const v8bf* B = (const v8bf*)(ws + OFF_B3T);
    #pragma unroll
    for (int kk = 0; kk < 8; kk++){
      v8bf bf = B[(kk*4 + wave)*64 + lane];
      #pragma unroll
      for (int m = 0; m < 4; m++){
        v8bf a = *(const v8bf*)&b2[m*16 + l16][kk*32 + quad*8];
        acc[m] = __builtin_amdgcn_mfma_f32_16x16x32_bf16(a, bf, acc[m], 0,0,0);
      }
    }
    int col = wave*16 + l16;
    float bvv = Vb3[col];
    #pragma unroll
    for (int m = 0; m < 4; m++){
      #pragma unroll
      for (int r = 0; r < 4; r++){
        float t = tanhf_fast(acc[m][r] + bvv);
        float sq = t * t;
        sq += __shfl_xor(sq, 1); sq += __shfl_xor(sq, 2);
        sq += __shfl_xor(sq, 4); sq += __shfl_xor(sq, 8);
        s3.b3[m*16 + quad*4 + r][col] = f2bf(t * (1.0f - t*t));
        if (l16 == 0) red[m*16 + quad*4 + r][wave] = sq;
      }
    }
  }
  __syncthreads();

  // t3 = a3' @ Vw3 ; epilogue t2' = t3*(1-a2^2) in place into b2. Also emit V.
  {
    f32x4 acc[4][2];
    #pragma unroll
    for (int m = 0; m < 4; m++){ f32x4 z={0.f,0.f,0.f,0.f}; acc[m][0]=z; acc[m][1]=z; }
    const v8bf* B = (const v8bf*)(ws + OFF_B3);
    #pragma unroll
    for (int kk = 0; kk < 2; kk++){
      v8bf a[4];
      #pragma unroll
      for (int m = 0; m < 4; m++)
        a[m] = *(const v8bf*)&s3.b3[m*16 + l16][kk*32 + quad*8];
      #pragma unroll
      for (int nt = 0; nt < 2; nt++){
        v8bf bf = B[(kk*16 + wave*2 + nt)*64 + lane];
        #pragma unroll
        for (int m = 0; m < 4; m++)
          acc[m][nt] = __builtin_amdgcn_mfma_f32_16x16x32_bf16(a[m], bf, acc[m][nt], 0,0,0);
      }
    }
    #pragma unroll
    for (int m = 0; m < 4; m++){
      int rb = m*16 + quad*4;
      #pragma unroll
      for (int nt = 0; nt < 2; nt++){
        int col = (wave*2 + nt)*16 + l16;
        #pragma unroll
        for (int r = 0; r < 4; r++){
          float a2v = (float)b2[rb + r][col];
          b2[rb + r][col] = f2bf(acc[m][nt][r] * (1.0f - a2v*a2v));
        }
      }
    }
    if (tid < RPB)
      out[BSZ + row0 + tid] = 0.5f * (red[tid][0] + red[tid][1] + red[tid][2] + red[tid][3]);
  }
  __syncthreads();

  gemm256(b2, ws + OFF_B2, nullptr, b1, 1);  // s2' = (t2'@Vw2)*(1-a1^2) -> b1 in place
  __syncthreads();
  mfma_reduce(b1, ws + OFF_GV, 4);           // grad_V partials -> r4 (b3 dead)
  __syncthreads();
  if (tid < 256){
    int b = tid >> 2, k2 = tid & 3;
    float s = 0.f;
    #pragma unroll
    for (int w = 0; w < 8; w++) s += s3.r4[w][b][k2];
    red[b][k2] = s;
  }
  __syncthreads();

  // dynamics + Vdot
  if (tid < RPB){
    float4 xv = xs4[tid];
    float th = xv.y, vv = xv.z, om = xv.w;
    float c = cosf(th), s = sinf(th);
    float dc  = c - 24.7f;
    float dc2 = c*c - 24.7f;
    float f2v = (c*(9.8f*s + 11.5f*vv) + 68.4f*vv - 1.2f*om*om*s) / dc;
    float f3v = (-58.8f*vv*c - 243.5f*vv - s*(208.3f + om*om*c)) / dc2;
    float g2v = (-1.8f*c - 10.9f) / dc;
    float g3v = (9.3f*c + 38.6f) / dc2;
    float Lf = red[tid][0]*vv + red[tid][1]*om + red[tid][2]*f2v + red[tid][3]*f3v;
    float Lg = red[tid][2]*g2v + red[tid][3]*g3v;
    out[2*BSZ + row0 + tid] = Lf + Lg * utile[tid];
  }
}

extern "C" void kernel_launch(void* const* d_in, const int* in_sizes, int n_in,
                              void* d_out, int out_size, void* d_ws, size_t ws_size,
                              hipStream_t stream) {
  const float* x   = (const float*)d_in[0];
  const float* Vw1 = (const float*)d_in[1];
  const float* Vb1 = (const float*)d_in[2];
  const float* Vw2 = (const float*)d_in[3];
  const float* Vb2 = (const float*)d_in[4];
  const float* Vw3 = (const float*)d_in[5];
  const float* Vb3 = (const float*)d_in[6];
  const float* Uw1 = (const float*)d_in[7];
  const float* Ub1 = (const float*)d_in[8];
  const float* Uw2 = (const float*)d_in[9];
  const float* Ub2 = (const float*)d_in[10];
  const float* Uw3 = (const float*)d_in[11];
  const float* Ub3 = (const float*)d_in[12];
  __bf16* ws = (__bf16*)d_ws;
  float* out = (float*)d_out;

  hipLaunchKernelGGL(prep_weights, dim3((WS_ELEMS + 255) / 256), dim3(256), 0, stream,
                     Vw2, Uw2, Vw3, Vw1, Uw3, ws);
  hipLaunchKernelGGL(fused_clf, dim3(BSZ / RPB), dim3(NTHREADS), 0, stream,
                     x, Vw1, Vb1, Vb2, Vb3, Uw1, Ub1, Ub2, Ub3, ws, out);
}

// Round 3
// 198.363 us; speedup vs baseline: 1.5852x; 1.0426x over previous
//
#include <hip/hip_runtime.h>
#include <hip/hip_bf16.h>

#define BSZ 131072

typedef __bf16 v8bf __attribute__((ext_vector_type(8)));
typedef float f32x4 __attribute__((ext_vector_type(4)));

constexpr int RPB = 64;        // rows per block
constexpr int NTHREADS = 512;  // 8 waves
constexpr int LDA = 264;       // 256 + 8 pad (528B rows, 16B aligned)

// d_ws layout (bf16 element offsets) — fragment-swizzled B operands
constexpr int OFF_B2T = 0;        // z2 : B[k][n] = Vw2[n][k]   (256x256) NT=16
constexpr int OFF_U2T = 65536;    // U2 : B[k][n] = Uw2[n][k]   (256x256) NT=16
constexpr int OFF_B2  = 131072;   // s2 : B[k][n] = Vw2[k][n]   (256x256) NT=16
constexpr int OFF_B3T = 196608;   // z3 : B[k][n] = Vw3[n][k]   (256x64)  NT=4
constexpr int OFF_B3  = 212992;   // t3 : B[k][n] = Vw3[k][n]   (64x256)  NT=16
constexpr int OFF_U3  = 229376;   // u3 : B[k][0] = Uw3[k], cols 1..15 zero (256x16) NT=1
constexpr int OFF_GV  = 233472;   // gV : B[k][n] = Vw1[k][n] n<4 else 0  (256x16) NT=1
constexpr int OFF_LV1 = 237568;   // L1V: B[k][n] = Vw1[n][k] k<4 else 0  (32x256)  NT=16
constexpr int OFF_LU1 = 245760;   // L1U: B[k][n] = Uw1[n][k] k<4 else 0  (32x256)  NT=16
constexpr int WS_ELEMS = 253952;

__device__ __forceinline__ float tanhf_fast(float x){
  float e = __expf(2.0f * x);
  return 1.0f - 2.0f / (e + 1.0f);   // exact at +-inf, no NaN
}

// cheap bf16 convert: round-half-away-from-zero, 2 VALU ops (vs ~5 for RNE lib call)
__device__ __forceinline__ __bf16 f2bf(float f){
  unsigned u = __builtin_bit_cast(unsigned, f);
  u += 0x8000u;
  unsigned short h = (unsigned short)(u >> 16);
  return __builtin_bit_cast(__bf16, h);
}

// ---- weight pre-swizzle: one thread per bf16 element of ws ----
// Fragment storage: frag f=(kstep*NT+ntile); lane l holds 8 contiguous bf16:
//   element j of lane l = B[kstep*32 + (l>>4)*8 + j][ntile*16 + (l&15)]
__global__ void prep_weights(const float* __restrict__ Vw2,
                             const float* __restrict__ Uw2,
                             const float* __restrict__ Vw3,
                             const float* __restrict__ Vw1,
                             const float* __restrict__ Uw1,
                             const float* __restrict__ Uw3,
                             __bf16* __restrict__ ws){
  int e = blockIdx.x * 256 + threadIdx.x;
  if (e >= WS_ELEMS) return;
  int idx, NT, base, mode; const float* W;
  if      (e <  65536){ idx = e;          W = Vw2; mode = 0; NT = 16; base = OFF_B2T; }
  else if (e < 131072){ idx = e - 65536;  W = Uw2; mode = 0; NT = 16; base = OFF_U2T; }
  else if (e < 196608){ idx = e - 131072; W = Vw2; mode = 1; NT = 16; base = OFF_B2;  }
  else if (e < 212992){ idx = e - 196608; W = Vw3; mode = 0; NT = 4;  base = OFF_B3T; }
  else if (e < 229376){ idx = e - 212992; W = Vw3; mode = 1; NT = 16; base = OFF_B3;  }
  else if (e < 233472){ idx = e - 229376; W = Uw3; mode = 2; NT = 1;  base = OFF_U3;  }
  else if (e < 237568){ idx = e - 233472; W = Vw1; mode = 3; NT = 1;  base = OFF_GV;  }
  else if (e < 245760){ idx = e - 237568; W = Vw1; mode = 4; NT = 16; base = OFF_LV1; }
  else                { idx = e - 245760; W = Uw1; mode = 4; NT = 16; base = OFF_LU1; }
  int j = idx & 7, l = (idx >> 3) & 63, f = idx >> 9;
  int nt = f % NT, ks = f / NT;
  int k = ks * 32 + (l >> 4) * 8 + j;
  int n = nt * 16 + (l & 15);
  float v;
  if      (mode == 0) v = W[n * 256 + k];
  else if (mode == 1) v = W[k * 256 + n];
  else if (mode == 2) v = (n == 0) ? W[k] : 0.0f;
  else if (mode == 3) v = (n < 4)  ? W[k * 4 + n] : 0.0f;
  else                v = (k < 4)  ? W[n * 4 + k] : 0.0f;
  ws[base + idx] = f2bf(v);
}

__global__ __launch_bounds__(NTHREADS, 4) void fused_clf(
    const float* __restrict__ x,
    const float* __restrict__ Vb1, const float* __restrict__ Vb2,
    const float* __restrict__ Vb3,
    const float* __restrict__ Ub1, const float* __restrict__ Ub2,
    const float* __restrict__ Ub3,
    const __bf16* __restrict__ ws,
    float* __restrict__ out)
{
  __shared__ __bf16 b1[RPB][LDA];     // u2 | a1 -> s2'
  __shared__ __bf16 b2[RPB][LDA];     // u1 | a2 -> t2'
  __shared__ union alignas(16) S3 {   // b3 live z3..t3; r4 live for the two reduces
    __bf16 b3[RPB][72];               // a3' = a3*(1-a3^2)
    float  r4[8][RPB][4];             // per-wave MFMA reduction partials
  } s3;
  __shared__ float  red[RPB][4];
  __shared__ float  utile[RPB];

  const int tid  = threadIdx.x;
  const int lane = tid & 63;
  const int wave = tid >> 6;       // 0..7
  const int quad = lane >> 4;
  const int l16  = lane & 15;
  const int row0 = blockIdx.x * RPB;

  // ---- x A-fragments (K=4 zero-padded to 32), built once, reused U & V ----
  v8bf xa[4];
  #pragma unroll
  for (int m = 0; m < 4; m++){
    v8bf z;
    #pragma unroll
    for (int j = 0; j < 8; j++) z[j] = (__bf16)0.0f;
    if (quad == 0){
      float4 xv = ((const float4*)x)[row0 + m*16 + l16];
      z[0] = f2bf(xv.x); z[1] = f2bf(xv.y); z[2] = f2bf(xv.z); z[3] = f2bf(xv.w);
    }
    xa[m] = z;
  }

  // ---- layer-1 via MFMA (single K-step) ----
  auto layer1m = [&](const __bf16* __restrict__ Bw, const float* __restrict__ bv,
                     __bf16 (*dst)[LDA]){
    const v8bf* B = (const v8bf*)Bw;
    v8bf bf0 = B[(wave*2 + 0)*64 + lane];
    v8bf bf1 = B[(wave*2 + 1)*64 + lane];
    f32x4 acc[4][2];
    #pragma unroll
    for (int m = 0; m < 4; m++){ f32x4 z={0.f,0.f,0.f,0.f}; acc[m][0]=z; acc[m][1]=z; }
    #pragma unroll
    for (int m = 0; m < 4; m++){
      acc[m][0] = __builtin_amdgcn_mfma_f32_16x16x32_bf16(xa[m], bf0, acc[m][0], 0,0,0);
      acc[m][1] = __builtin_amdgcn_mfma_f32_16x16x32_bf16(xa[m], bf1, acc[m][1], 0,0,0);
    }
    #pragma unroll
    for (int m = 0; m < 4; m++){
      int rb = m*16 + quad*4;
      #pragma unroll
      for (int nt = 0; nt < 2; nt++){
        int col = (wave*2 + nt)*16 + l16;
        float bvv = bv[col];
        #pragma unroll
        for (int r = 0; r < 4; r++)
          dst[rb + r][col] = f2bf(tanhf_fast(acc[m][nt][r] + bvv));
      }
    }
  };

  // ---- (64x256)x(256x256): wave = 2 n-tiles, all 4 m-tiles ----
  auto gemm256 = [&](const __bf16 (*A)[LDA], const __bf16* __restrict__ Bw,
                     const float* __restrict__ bias, __bf16 (*dst)[LDA], int epi){
    f32x4 acc[4][2];
    #pragma unroll
    for (int m = 0; m < 4; m++){ f32x4 z={0.f,0.f,0.f,0.f}; acc[m][0]=z; acc[m][1]=z; }
    const v8bf* B = (const v8bf*)Bw;
    #pragma unroll
    for (int kk = 0; kk < 8; kk++){
      v8bf a[4];
      #pragma unroll
      for (int m = 0; m < 4; m++)
        a[m] = *(const v8bf*)&A[m*16 + l16][kk*32 + quad*8];
      #pragma unroll
      for (int nt = 0; nt < 2; nt++){
        v8bf bf = B[(kk*16 + wave*2 + nt)*64 + lane];
        #pragma unroll
        for (int m = 0; m < 4; m++)
          acc[m][nt] = __builtin_amdgcn_mfma_f32_16x16x32_bf16(a[m], bf, acc[m][nt], 0,0,0);
      }
    }
    #pragma unroll
    for (int m = 0; m < 4; m++){
      int rb = m*16 + quad*4;
      #pragma unroll
      for (int nt = 0; nt < 2; nt++){
        int col = (wave*2 + nt)*16 + l16;
        float bvv = (epi == 0) ? bias[col] : 0.0f;
        #pragma unroll
        for (int r = 0; r < 4; r++){
          float v = acc[m][nt][r] + bvv;
          if (epi == 0){
            dst[rb + r][col] = f2bf(tanhf_fast(v));
          } else {
            float a1v = (float)dst[rb + r][col];
            dst[rb + r][col] = f2bf(v * (1.0f - a1v*a1v));
          }
        }
      }
    }
  };

  // ---- N=16 MFMA reduction partial: K split across 8 waves ----
  auto mfma_reduce = [&](const __bf16 (*A)[LDA], const __bf16* __restrict__ Bw,
                         int ncols){
    f32x4 acc[4];
    #pragma unroll
    for (int m = 0; m < 4; m++){ f32x4 z={0.f,0.f,0.f,0.f}; acc[m]=z; }
    const v8bf* B = (const v8bf*)Bw;
    v8bf bf = B[wave*64 + lane];           // frag ks = wave (NT=1)
    #pragma unroll
    for (int m = 0; m < 4; m++){
      v8bf a = *(const v8bf*)&A[m*16 + l16][wave*32 + quad*8];
      acc[m] = __builtin_amdgcn_mfma_f32_16x16x32_bf16(a, bf, acc[m], 0,0,0);
    }
    if (l16 < ncols){
      #pragma unroll
      for (int m = 0; m < 4; m++)
        #pragma unroll
        for (int r = 0; r < 4; r++)
          s3.r4[wave][m*16 + quad*4 + r][l16] = acc[m][r];
    }
  };

  // ================= U network =================
  layer1m(ws + OFF_LU1, Ub1, b2);          // u1 -> b2
  __syncthreads();
  gemm256(b2, ws + OFF_U2T, Ub2, b1, 0);   // u2 -> b1
  __syncthreads();
  mfma_reduce(b1, ws + OFF_U3, 1);         // u2 . Uw3 partials -> r4
  __syncthreads();
  if (tid < RPB){                          // wave 0: finish u
    float z = Ub3[0];
    #pragma unroll
    for (int w = 0; w < 8; w++) z += s3.r4[w][tid][0];
    float u = tanhf_fast(z) * 20.0f;
    utile[tid] = u;
    out[row0 + tid] = u;
  }
  // ================= V network =================
  layer1m(ws + OFF_LV1, Vb1, b1);          // a1 -> b1 (u2 consumed)
  __syncthreads();
  gemm256(b1, ws + OFF_B2T, Vb2, b2, 0);   // a2 -> b2
  __syncthreads();

  // z3: a2 @ Vw3^T -> a3. All 8 waves: wave = (m-pair, n-tile).
  // Fused: V row-partials via shfl butterfly; store a3' = a3*(1-a3^2).
  {
    const int mp = wave >> 2;     // 0..1
    const int nt = wave & 3;      // 0..3
    f32x4 acc[2];
    { f32x4 z={0.f,0.f,0.f,0.f}; acc[0]=z; acc[1]=z; }
    const v8bf* B = (const v8bf*)(ws + OFF_B3T);
    #pragma unroll
    for (int kk = 0; kk < 8; kk++){
      v8bf bf = B[(kk*4 + nt)*64 + lane];
      #pragma unroll
      for (int m2 = 0; m2 < 2; m2++){
        v8bf a = *(const v8bf*)&b2[(mp*2 + m2)*16 + l16][kk*32 + quad*8];
        acc[m2] = __builtin_amdgcn_mfma_f32_16x16x32_bf16(a, bf, acc[m2], 0,0,0);
      }
    }
    int col = nt*16 + l16;
    float bvv = Vb3[col];
    #pragma unroll
    for (int m2 = 0; m2 < 2; m2++){
      #pragma unroll
      for (int r = 0; r < 4; r++){
        int row = (mp*2 + m2)*16 + quad*4 + r;
        float t = tanhf_fast(acc[m2][r] + bvv);
        float sq = t * t;
        sq += __shfl_xor(sq, 1); sq += __shfl_xor(sq, 2);
        sq += __shfl_xor(sq, 4); sq += __shfl_xor(sq, 8);
        s3.b3[row][col] = f2bf(t * (1.0f - t*t));
        if (l16 == 0) red[row][nt] = sq;
      }
    }
  }
  __syncthreads();

  // t3 = a3' @ Vw3 ; epilogue t2' = t3*(1-a2^2) in place into b2. Also emit V.
  {
    f32x4 acc[4][2];
    #pragma unroll
    for (int m = 0; m < 4; m++){ f32x4 z={0.f,0.f,0.f,0.f}; acc[m][0]=z; acc[m][1]=z; }
    const v8bf* B = (const v8bf*)(ws + OFF_B3);
    #pragma unroll
    for (int kk = 0; kk < 2; kk++){
      v8bf a[4];
      #pragma unroll
      for (int m = 0; m < 4; m++)
        a[m] = *(const v8bf*)&s3.b3[m*16 + l16][kk*32 + quad*8];
      #pragma unroll
      for (int nt = 0; nt < 2; nt++){
        v8bf bf = B[(kk*16 + wave*2 + nt)*64 + lane];
        #pragma unroll
        for (int m = 0; m < 4; m++)
          acc[m][nt] = __builtin_amdgcn_mfma_f32_16x16x32_bf16(a[m], bf, acc[m][nt], 0,0,0);
      }
    }
    #pragma unroll
    for (int m = 0; m < 4; m++){
      int rb = m*16 + quad*4;
      #pragma unroll
      for (int nt = 0; nt < 2; nt++){
        int col = (wave*2 + nt)*16 + l16;
        #pragma unroll
        for (int r = 0; r < 4; r++){
          float a2v = (float)b2[rb + r][col];
          b2[rb + r][col] = f2bf(acc[m][nt][r] * (1.0f - a2v*a2v));
        }
      }
    }
    if (tid < RPB)
      out[BSZ + row0 + tid] = 0.5f * (red[tid][0] + red[tid][1] + red[tid][2] + red[tid][3]);
  }
  __syncthreads();

  gemm256(b2, ws + OFF_B2, nullptr, b1, 1);  // s2' = (t2'@Vw2)*(1-a1^2) -> b1
  __syncthreads();
  mfma_reduce(b1, ws + OFF_GV, 4);           // grad_V partials -> r4 (b3 dead)
  __syncthreads();
  if (tid < 256){
    int b = tid >> 2, k2 = tid & 3;
    float s = 0.f;
    #pragma unroll
    for (int w = 0; w < 8; w++) s += s3.r4[w][b][k2];
    red[b][k2] = s;
  }
  __syncthreads();

  // dynamics + Vdot
  if (tid < RPB){
    float4 xv = ((const float4*)x)[row0 + tid];
    float th = xv.y, vv = xv.z, om = xv.w;
    float c = cosf(th), s = sinf(th);
    float dc  = c - 24.7f;
    float dc2 = c*c - 24.7f;
    float f2v = (c*(9.8f*s + 11.5f*vv) + 68.4f*vv - 1.2f*om*om*s) / dc;
    float f3v = (-58.8f*vv*c - 243.5f*vv - s*(208.3f + om*om*c)) / dc2;
    float g2v = (-1.8f*c - 10.9f) / dc;
    float g3v = (9.3f*c + 38.6f) / dc2;
    float Lf = red[tid][0]*vv + red[tid][1]*om + red[tid][2]*f2v + red[tid][3]*f3v;
    float Lg = red[tid][2]*g2v + red[tid][3]*g3v;
    out[2*BSZ + row0 + tid] = Lf + Lg * utile[tid];
  }
}

extern "C" void kernel_launch(void* const* d_in, const int* in_sizes, int n_in,
                              void* d_out, int out_size, void* d_ws, size_t ws_size,
                              hipStream_t stream) {
  const float* x   = (const float*)d_in[0];
  const float* Vw1 = (const float*)d_in[1];
  const float* Vb1 = (const float*)d_in[2];
  const float* Vw2 = (const float*)d_in[3];
  const float* Vb2 = (const float*)d_in[4];
  const float* Vw3 = (const float*)d_in[5];
  const float* Vb3 = (const float*)d_in[6];
  const float* Uw1 = (const float*)d_in[7];
  const float* Ub1 = (const float*)d_in[8];
  const float* Uw2 = (const float*)d_in[9];
  const float* Ub2 = (const float*)d_in[10];
  const float* Uw3 = (const float*)d_in[11];
  const float* Ub3 = (const float*)d_in[12];
  __bf16* ws = (__bf16*)d_ws;
  float* out = (float*)d_out;

  hipLaunchKernelGGL(prep_weights, dim3((WS_ELEMS + 255) / 256), dim3(256), 0, stream,
                     Vw2, Uw2, Vw3, Vw1, Uw1, Uw3, ws);
  hipLaunchKernelGGL(fused_clf, dim3(BSZ / RPB), dim3(NTHREADS), 0, stream,
                     x, Vb1, Vb2, Vb3, Ub1, Ub2, Ub3, ws, out);
}